// Round 2
// baseline (181.234 us; speedup 1.0000x reference)
//
#include <hip/hip_runtime.h>
#include <hip/hip_bf16.h>
#include <hip/hip_fp16.h>

#define Bn 2048
#define Tn 128
#define Vn 256
#define Cn 32
#define Hn 128
#define En 256
#define On 256
#define Gn 384
#define BNn 32

typedef _Float16 f16;
typedef __attribute__((ext_vector_type(8))) _Float16 h8;
typedef __attribute__((ext_vector_type(4))) float f4;

__device__ __forceinline__ h8 ld_f32x8_as_h8(const float* p) {
  h8 r;
#pragma unroll
  for (int i = 0; i < 8; ++i) r[i] = (f16)p[i];
  return r;
}

// ---------------- Kernel 1: xp lookup tables ----------------
// xt[dir][v][g] = sum_c emb[v][c]*w_ih[g][c] + b_ih[g], stored f16
__global__ void build_table_k(const float* __restrict__ emb,
                              const float* __restrict__ wf,
                              const float* __restrict__ bfv,
                              const float* __restrict__ wb,
                              const float* __restrict__ bbv,
                              f16* __restrict__ xt) {
  const int dir = blockIdx.x >> 8;
  const int v = blockIdx.x & 255;
  const int g = threadIdx.x;  // 384 threads
  const float* w = dir ? wb : wf;
  const float* bi = dir ? bbv : bfv;
  float acc = bi[g];
#pragma unroll
  for (int c = 0; c < Cn; ++c)
    acc = fmaf(emb[v * Cn + c], w[g * Cn + c], acc);
  xt[(dir * Vn + v) * Gn + g] = (f16)acc;
}

// ---------------- Kernel 2: bidirectional GRU ----------------
// grid 256: dir = blockIdx&1, 16 samples/block, 8 waves, wave wv owns j in [wv*16, wv*16+16)
__launch_bounds__(512, 2)
__global__ void gru_k(const int* __restrict__ tokens,
                      const float* __restrict__ whhf,
                      const float* __restrict__ bhhf,
                      const float* __restrict__ whhb,
                      const float* __restrict__ bhhb,
                      const f16* __restrict__ xt,
                      float* __restrict__ feat) {
  const int dir = blockIdx.x & 1;
  const int b0 = (blockIdx.x >> 1) * 16;
  const int tid = threadIdx.x;
  const int wv = tid >> 6;
  const int ln = tid & 63;
  const int lr = ln & 15;   // MFMA A-row / C-col index
  const int lg = ln >> 4;   // k-group
  const int j0 = wv * 16;

  __shared__ f16 hbuf[16][136];  // h state, f16, padded row stride (272B, 16B-aligned)
  __shared__ int tokl[16 * 128];

  for (int i = tid; i < 16 * 128; i += 512)
    tokl[i] = tokens[(b0 + (i >> 7)) * Tn + (i & 127)];
  for (int i = tid; i < 16 * 136; i += 512) (&hbuf[0][0])[i] = (f16)0.f;

  const float* whh = dir ? whhb : whhf;
  const float* bhh = dir ? bhhb : bhhf;
  const f16* tab = xt + dir * (Vn * Gn);

  // B-frags for w_hh, resident in registers for the whole T loop.
  // B[k][n] = w_hh[g0+n][k]; lane holds n=lr, k = kk*32 + lg*8 + i
  h8 Bf[3][4];
#pragma unroll
  for (int ga = 0; ga < 3; ++ga) {
    const float* wr = whh + (ga * Hn + j0 + lr) * Hn + lg * 8;
#pragma unroll
    for (int kk = 0; kk < 4; ++kk) Bf[ga][kk] = ld_f32x8_as_h8(wr + kk * 32);
  }
  const float bh0 = bhh[j0 + lr];
  const float bh1 = bhh[Hn + j0 + lr];
  const float bh2 = bhh[2 * Hn + j0 + lr];

  __syncthreads();

  // prefetch xp for t=0
  float cxr[4], cxz[4], cxn[4];
  {
    const int tt = dir ? (Tn - 1) : 0;
#pragma unroll
    for (int r = 0; r < 4; ++r) {
      const int tok = tokl[(lg * 4 + r) * 128 + tt];
      const f16* base = tab + tok * Gn + j0 + lr;
      cxr[r] = (float)base[0];
      cxz[r] = (float)base[Hn];
      cxn[r] = (float)base[2 * Hn];
    }
  }

  for (int t = 0; t < Tn; ++t) {
    // prefetch xp for t+1 (clamped; loads issued early, consumed next iter)
    const int tn1 = (t + 1 < Tn) ? (t + 1) : t;
    const int tt2 = dir ? (Tn - 1 - tn1) : tn1;
    float nxr[4], nxz[4], nxn[4];
#pragma unroll
    for (int r = 0; r < 4; ++r) {
      const int tok = tokl[(lg * 4 + r) * 128 + tt2];
      const f16* base = tab + tok * Gn + j0 + lr;
      nxr[r] = (float)base[0];
      nxz[r] = (float)base[Hn];
      nxn[r] = (float)base[2 * Hn];
    }

    // gh = h @ w_hh^T + b_hh   (acc initialized with b_hh)
    f4 aR = {bh0, bh0, bh0, bh0};
    f4 aZ = {bh1, bh1, bh1, bh1};
    f4 aN = {bh2, bh2, bh2, bh2};
#pragma unroll
    for (int kk = 0; kk < 4; ++kk) {
      h8 a = *(const h8*)(&hbuf[lr][kk * 32 + lg * 8]);
      aR = __builtin_amdgcn_mfma_f32_16x16x32_f16(a, Bf[0][kk], aR, 0, 0, 0);
      aZ = __builtin_amdgcn_mfma_f32_16x16x32_f16(a, Bf[1][kk], aZ, 0, 0, 0);
      aN = __builtin_amdgcn_mfma_f32_16x16x32_f16(a, Bf[2][kk], aN, 0, 0, 0);
    }

    // gates; C layout: row m = lg*4+r (sample), col j = j0+lr (hidden idx)
    float hnew[4];
#pragma unroll
    for (int r = 0; r < 4; ++r) {
      const int m = lg * 4 + r;
      const float p_r = cxr[r] + aR[r];
      const float p_z = cxz[r] + aZ[r];
      const float rg = __builtin_amdgcn_rcpf(1.0f + __expf(-p_r));
      const float zg = __builtin_amdgcn_rcpf(1.0f + __expf(-p_z));
      const float p_n = fmaf(rg, aN[r], cxn[r]);
      const float ng = 1.0f - 2.0f * __builtin_amdgcn_rcpf(1.0f + __expf(2.0f * p_n));
      const float hold = (float)hbuf[m][j0 + lr];
      hnew[r] = fmaf(zg, hold - ng, ng);
    }
#pragma unroll
    for (int r = 0; r < 4; ++r) { cxr[r] = nxr[r]; cxz[r] = nxz[r]; cxn[r] = nxn[r]; }

    __syncthreads();  // all waves done reading old h
#pragma unroll
    for (int r = 0; r < 4; ++r) hbuf[lg * 4 + r][j0 + lr] = (f16)hnew[r];
    __syncthreads();  // new h visible
  }

  for (int i = tid; i < 16 * Hn; i += 512) {
    const int m = i >> 7, j = i & 127;
    feat[(b0 + m) * En + dir * Hn + j] = (float)hbuf[m][j];
  }
}

// ---------------- Kernel 3: adapter + LN + proj ----------------
// 128 blocks x 256 threads; 16 samples/block; wave wv handles samples wv*4..wv*4+3,
// then all 4 waves do the 256x256 proj via f16 MFMA.
__launch_bounds__(256, 2)
__global__ void epi_k(const float* __restrict__ feat,
                      const int* __restrict__ lang_ids,
                      const float* __restrict__ down_w,
                      const float* __restrict__ down_b,
                      const float* __restrict__ up_w,
                      const float* __restrict__ up_b,
                      const float* __restrict__ ln_g,
                      const float* __restrict__ ln_b,
                      const float* __restrict__ proj_w,
                      const float* __restrict__ proj_b,
                      float* __restrict__ out) {
  const int tid = threadIdx.x;
  const int wv = tid >> 6, ln = tid & 63;
  const int b0 = blockIdx.x * 16;

  __shared__ float fl[16][En];        // feat staging
  __shared__ f16 yA[16][En + 8];      // LN output, MFMA A layout (padded vs bank conflicts)

#pragma unroll 1
  for (int s = 0; s < 16; ++s) fl[s][tid] = feat[(b0 + s) * En + tid];
  __syncthreads();

#pragma unroll 1
  for (int si = 0; si < 4; ++si) {
    const int s = wv * 4 + si;
    const int b = b0 + s;
    const int lang = lang_ids[b];

    // down: lane: d = ln&31, half = ln>>5 handles 128 elems
    const int d = ln & 31, hf = ln >> 5;
    const float* dw = down_w + (lang * BNn + d) * En + hf * 128;
    const float* fsrc = &fl[s][hf * 128];
    float p = 0.f;
#pragma unroll 8
    for (int e = 0; e < 128; ++e) p = fmaf(fsrc[e], dw[e], p);
    p += __shfl_xor(p, 32);
    const float hv = p + down_b[lang * BNn + d];
    const float hid = 0.5f * hv * (1.0f + erff(hv * 0.70710678118f));  // exact gelu

    // up + residual: lane owns e = ln*4 .. ln*4+3
    const int e0 = ln * 4;
    float a0 = 0.f, a1 = 0.f, a2 = 0.f, a3 = 0.f;
    const float* uw = up_w + (lang * En + e0) * BNn;
#pragma unroll
    for (int dd = 0; dd < 32; ++dd) {
      const float hdd = __shfl(hid, dd);
      a0 = fmaf(hdd, uw[0 * BNn + dd], a0);
      a1 = fmaf(hdd, uw[1 * BNn + dd], a1);
      a2 = fmaf(hdd, uw[2 * BNn + dd], a2);
      a3 = fmaf(hdd, uw[3 * BNn + dd], a3);
    }
    float x[4] = {a0, a1, a2, a3};
    float s1 = 0.f, s2 = 0.f;
#pragma unroll
    for (int i = 0; i < 4; ++i) {
      x[i] += fl[s][e0 + i] + up_b[lang * En + e0 + i];
      s1 += x[i];
      s2 = fmaf(x[i], x[i], s2);
    }
#pragma unroll
    for (int off = 32; off >= 1; off >>= 1) {
      s1 += __shfl_xor(s1, off);
      s2 += __shfl_xor(s2, off);
    }
    const float mu = s1 * (1.0f / En);
    const float var = s2 * (1.0f / En) - mu * mu;
    const float rs = rsqrtf(var + 1e-5f);
#pragma unroll
    for (int i = 0; i < 4; ++i) {
      const float yv = (x[i] - mu) * rs * ln_g[lang * En + e0 + i] + ln_b[lang * En + e0 + i];
      yA[s][e0 + i] = (f16)yv;
    }
  }
  __syncthreads();

  // proj: wave wv covers o in [wv*64, wv*64+64)
  const int lr = ln & 15, lg = ln >> 4;
  f4 acc[4];
#pragma unroll
  for (int tt = 0; tt < 4; ++tt) {
    const float pb = proj_b[wv * 64 + tt * 16 + lr];
    acc[tt] = (f4){pb, pb, pb, pb};
  }
#pragma unroll
  for (int kk = 0; kk < 8; ++kk) {
    h8 aF = *(const h8*)(&yA[lr][kk * 32 + lg * 8]);
#pragma unroll
    for (int tt = 0; tt < 4; ++tt) {
      const int o0 = wv * 64 + tt * 16;
      h8 bF = ld_f32x8_as_h8(proj_w + (o0 + lr) * En + kk * 32 + lg * 8);
      acc[tt] = __builtin_amdgcn_mfma_f32_16x16x32_f16(aF, bF, acc[tt], 0, 0, 0);
    }
  }
#pragma unroll
  for (int tt = 0; tt < 4; ++tt) {
    const int o0 = wv * 64 + tt * 16;
#pragma unroll
    for (int r = 0; r < 4; ++r)
      out[(b0 + lg * 4 + r) * On + o0 + lr] = acc[tt][r];
  }
}

extern "C" void kernel_launch(void* const* d_in, const int* in_sizes, int n_in,
                              void* d_out, int out_size, void* d_ws, size_t ws_size,
                              hipStream_t stream) {
  const int* tokens = (const int*)d_in[0];
  const int* lang_ids = (const int*)d_in[1];
  const float* emb = (const float*)d_in[2];
  const float* w_ih_f = (const float*)d_in[3];
  const float* w_hh_f = (const float*)d_in[4];
  const float* b_ih_f = (const float*)d_in[5];
  const float* b_hh_f = (const float*)d_in[6];
  const float* w_ih_b = (const float*)d_in[7];
  const float* w_hh_b = (const float*)d_in[8];
  const float* b_ih_b = (const float*)d_in[9];
  const float* b_hh_b = (const float*)d_in[10];
  const float* down_w = (const float*)d_in[11];
  const float* down_b = (const float*)d_in[12];
  const float* up_w = (const float*)d_in[13];
  const float* up_b = (const float*)d_in[14];
  const float* ln_g = (const float*)d_in[15];
  const float* ln_b = (const float*)d_in[16];
  const float* proj_w = (const float*)d_in[17];
  const float* proj_b = (const float*)d_in[18];

  f16* xt = (f16*)d_ws;                                      // [2][256][384] f16
  float* feat = (float*)((char*)d_ws + 2 * Vn * Gn * 2);     // [2048][256] f32

  build_table_k<<<dim3(512), dim3(384), 0, stream>>>(emb, w_ih_f, b_ih_f, w_ih_b, b_ih_b, xt);
  gru_k<<<dim3(256), dim3(512), 0, stream>>>(tokens, w_hh_f, b_hh_f, w_hh_b, b_hh_b, xt, feat);
  epi_k<<<dim3(128), dim3(256), 0, stream>>>(feat, lang_ids, down_w, down_b, up_w, up_b,
                                             ln_g, ln_b, proj_w, proj_b, (float*)d_out);
}

// Round 3
// 141.040 us; speedup vs baseline: 1.2850x; 1.2850x over previous
//
#include <hip/hip_runtime.h>
#include <hip/hip_bf16.h>
#include <hip/hip_fp16.h>

#define Bn 2048
#define Tn 128
#define Vn 256
#define Cn 32
#define Hn 128
#define En 256
#define On 256
#define Gn 384
#define BNn 32

typedef _Float16 f16;
typedef __attribute__((ext_vector_type(8))) _Float16 h8;
typedef __attribute__((ext_vector_type(4))) _Float16 h4;
typedef __attribute__((ext_vector_type(4))) float f4;

#define LOG2E 1.4426950408889634f

__device__ __forceinline__ float fexp2(float x) { return __builtin_amdgcn_exp2f(x); }
__device__ __forceinline__ float frcp(float x) { return __builtin_amdgcn_rcpf(x); }

// ---------------- Kernel 1: packed scaled xp table ----------------
// xt[dir][v][j][4] = { -log2e*(xr+bir), -log2e*(xz+biz), 2log2e*(xn+bin), 0 }
__global__ void build_table_k(const float* __restrict__ emb,
                              const float* __restrict__ wf,
                              const float* __restrict__ bfv,
                              const float* __restrict__ wb,
                              const float* __restrict__ bbv,
                              f16* __restrict__ xt) {
  const int dir = blockIdx.x >> 8;
  const int v = blockIdx.x & 255;
  const int j = threadIdx.x;  // 128 threads
  const float* w = dir ? wb : wf;
  const float* bi = dir ? bbv : bfv;
  const float sc[3] = {-LOG2E, -LOG2E, 2.0f * LOG2E};
  h4 o;
  o[3] = (f16)0.f;
#pragma unroll
  for (int ga = 0; ga < 3; ++ga) {
    const int g = ga * Hn + j;
    float acc = bi[g];
    const f4* wr = (const f4*)(w + g * Cn);
    const f4* er = (const f4*)(emb + v * Cn);
#pragma unroll
    for (int q = 0; q < 8; ++q) {
      f4 wv = wr[q], ev = er[q];
      acc = fmaf(ev.x, wv.x, acc);
      acc = fmaf(ev.y, wv.y, acc);
      acc = fmaf(ev.z, wv.z, acc);
      acc = fmaf(ev.w, wv.w, acc);
    }
    o[ga] = (f16)(acc * sc[ga]);
  }
  *(h4*)&xt[((dir * Vn + v) * Hn + j) * 4] = o;
}

// ---------------- Kernel 2: bidirectional GRU ----------------
// grid 256: dir = blockIdx&1, 16 samples/block, 8 waves, wave wv owns j in [wv*16, wv*16+16)
// h stored fragment-major: byte = (k>>3)*256 + m*16 + (k&7)*2, double-buffered.
__launch_bounds__(512, 2)
__global__ void gru_k(const int* __restrict__ tokens,
                      const float* __restrict__ whhf,
                      const float* __restrict__ bhhf,
                      const float* __restrict__ whhb,
                      const float* __restrict__ bhhb,
                      const f16* __restrict__ xt,
                      float* __restrict__ feat) {
  const int dir = blockIdx.x & 1;
  const int b0 = (blockIdx.x >> 1) * 16;
  const int tid = threadIdx.x;
  const int wv = tid >> 6;
  const int ln = tid & 63;
  const int lr = ln & 15;   // A row / C col
  const int lg = ln >> 4;   // k group / C row group
  const int j0 = wv * 16;
  const int j = j0 + lr;

  __shared__ f16 hfrag[2 * 2048];   // 2 bufs x [16 q][16 m][8 e]  (4KB each)
  __shared__ f16 xstg[2 * 8192];    // 2 bufs x [16 s][128 j][4]   (16KB each)
  __shared__ int tokl[16 * 128];

  for (int i = tid; i < 16 * 128; i += 512)
    tokl[i] = tokens[(b0 + (i >> 7)) * Tn + (i & 127)];
  for (int i = tid; i < 2 * 2048; i += 512) hfrag[i] = (f16)0.f;

  const float* whh = dir ? whhb : whhf;
  const float* bhh = dir ? bhhb : bhhf;
  const f16* tab = xt + dir * (Vn * Hn * 4);

  // register-resident B frags, gate-scaled at load
  const float gsc[3] = {-LOG2E, -LOG2E, 2.0f * LOG2E};
  h8 Bf[3][4];
#pragma unroll
  for (int ga = 0; ga < 3; ++ga) {
    const float* wr = whh + (ga * Hn + j) * Hn + lg * 8;
#pragma unroll
    for (int kk = 0; kk < 4; ++kk) {
      h8 b;
#pragma unroll
      for (int i = 0; i < 8; ++i) b[i] = (f16)(wr[kk * 32 + i] * gsc[ga]);
      Bf[ga][kk] = b;
    }
  }
  const float bh0 = bhh[j] * (-LOG2E);
  const float bh1 = bhh[Hn + j] * (-LOG2E);
  const float bh2 = bhh[2 * Hn + j] * (2.0f * LOG2E);

  // staging role: thread covers 32B of sample ss's row
  const int ss = tid >> 5;
  const int sq = tid & 31;

  // pre-stage t=0 into xstg buf 0
  {
    const int tt = dir ? (Tn - 1) : 0;
    const int tok = tokl[ss * 128 + tt];
    const h8* src = (const h8*)(tab + tok * 512 + sq * 16);
    h8 v0 = src[0], v1 = src[1];
    *(h8*)&xstg[ss * 512 + sq * 16] = v0;
    *(h8*)&xstg[ss * 512 + sq * 16 + 8] = v1;
  }
  __syncthreads();

  // per-thread constant LDS byte offsets
  const int aoff = lg * 256 + lr * 16;                    // A-frag read (+ kk*1024)
  const int woff = (j >> 3) * 256 + (j & 7) * 2 + lg * 64; // h write (+ r*16)
  const int xoff = lg * 4096 + j * 8;                      // xp read (+ r*1024)

  float hprev[4] = {0.f, 0.f, 0.f, 0.f};
  int p = 0;

  for (int t = 0; t < Tn; ++t) {
    const int cur = t & 1, nxt = cur ^ 1;
    // issue staged loads for t+1 early
    const int tn = (t + 1 < Tn) ? (t + 1) : t;
    const int tt2 = dir ? (Tn - 1 - tn) : tn;
    const int tok2 = tokl[ss * 128 + tt2];
    const h8* src = (const h8*)(tab + tok2 * 512 + sq * 16);
    h8 v0 = src[0], v1 = src[1];

    // A frags from hfrag[p]
    const char* hb = (const char*)hfrag + p * 4096;
    h8 Af[4];
#pragma unroll
    for (int kk = 0; kk < 4; ++kk)
      Af[kk] = *(const h8*)(hb + kk * 1024 + aoff);

    f4 aR = {bh0, bh0, bh0, bh0};
    f4 aZ = {bh1, bh1, bh1, bh1};
    f4 aN = {bh2, bh2, bh2, bh2};
#pragma unroll
    for (int kk = 0; kk < 4; ++kk) {
      aR = __builtin_amdgcn_mfma_f32_16x16x32_f16(Af[kk], Bf[0][kk], aR, 0, 0, 0);
      aZ = __builtin_amdgcn_mfma_f32_16x16x32_f16(Af[kk], Bf[1][kk], aZ, 0, 0, 0);
      aN = __builtin_amdgcn_mfma_f32_16x16x32_f16(Af[kk], Bf[2][kk], aN, 0, 0, 0);
    }

    // gates; element (m = lg*4+r, j); xp pre-scaled, aR/aZ/aN pre-scaled
    const char* xb = (const char*)xstg + cur * 16384;
    char* hw = (char*)hfrag + (p ^ 1) * 4096;
#pragma unroll
    for (int r = 0; r < 4; ++r) {
      h4 xv = *(const h4*)(xb + xoff + r * 1024);
      const float sr = (float)xv[0], sz = (float)xv[1], sn = (float)xv[2];
      const float rg = frcp(1.0f + fexp2(sr + aR[r]));
      const float zg = frcp(1.0f + fexp2(sz + aZ[r]));
      const float ng = fmaf(-2.0f, frcp(1.0f + fexp2(fmaf(rg, aN[r], sn))), 1.0f);
      const float hn_ = fmaf(zg, hprev[r] - ng, ng);
      hprev[r] = hn_;
      *(f16*)(hw + woff + r * 16) = (f16)hn_;
    }

    // write staged xp for t+1
    *(h8*)((char*)xstg + nxt * 16384 + ss * 1024 + sq * 32) = v0;
    *(h8*)((char*)xstg + nxt * 16384 + ss * 1024 + sq * 32 + 16) = v1;

    __syncthreads();
    p ^= 1;
  }

  // final h is in registers
#pragma unroll
  for (int r = 0; r < 4; ++r)
    feat[(b0 + lg * 4 + r) * En + dir * Hn + j] = hprev[r];
}

// ---------------- Kernel 3: adapter + LN + proj ----------------
// 256 blocks x 256 threads; 8 samples/block; wave wv: adapter for samples {2wv, 2wv+1},
// then proj o-range [wv*64, wv*64+64) via f16 MFMA (M=16 tile, rows 8-15 zero).
__launch_bounds__(256, 2)
__global__ void epi_k(const float* __restrict__ feat,
                      const int* __restrict__ lang_ids,
                      const float* __restrict__ down_w,
                      const float* __restrict__ down_b,
                      const float* __restrict__ up_w,
                      const float* __restrict__ up_b,
                      const float* __restrict__ ln_g,
                      const float* __restrict__ ln_b,
                      const float* __restrict__ proj_w,
                      const float* __restrict__ proj_b,
                      float* __restrict__ out) {
  const int tid = threadIdx.x;
  const int wv = tid >> 6, ln = tid & 63;
  const int b0 = blockIdx.x * 8;

  __shared__ float fl[8][En];
  __shared__ f16 yA[16][En + 8];

#pragma unroll
  for (int s = 0; s < 8; ++s) fl[s][tid] = feat[(b0 + s) * En + tid];
  {
    f16* z = &yA[0][0];
    for (int i = tid; i < 16 * (En + 8); i += 256) z[i] = (f16)0.f;
  }
  __syncthreads();

#pragma unroll 1
  for (int si = 0; si < 2; ++si) {
    const int s = wv * 2 + si;
    const int lang = lang_ids[b0 + s];

    // down: d = ln&31, two halves reduced via shfl
    const int d = ln & 31, hf = ln >> 5;
    const f4* dwv = (const f4*)(down_w + (lang * BNn + d) * En + hf * 128);
    const f4* fsv = (const f4*)&fl[s][hf * 128];
    float pacc = 0.f;
#pragma unroll
    for (int q = 0; q < 32; ++q) {
      f4 a = fsv[q], w = dwv[q];
      pacc = fmaf(a.x, w.x, pacc);
      pacc = fmaf(a.y, w.y, pacc);
      pacc = fmaf(a.z, w.z, pacc);
      pacc = fmaf(a.w, w.w, pacc);
    }
    pacc += __shfl_xor(pacc, 32);
    const float hv = pacc + down_b[lang * BNn + d];
    const float hid = 0.5f * hv * (1.0f + erff(hv * 0.70710678118f));

    // broadcast all 32 hid values
    float hh[32];
#pragma unroll
    for (int dd = 0; dd < 32; ++dd) hh[dd] = __shfl(hid, dd);

    // up + residual + LN; lane owns e = ln*4..ln*4+3
    const int e0 = ln * 4;
    float x[4];
    float s1 = 0.f, s2 = 0.f;
#pragma unroll
    for (int i = 0; i < 4; ++i) {
      const f4* ur = (const f4*)(up_w + (lang * En + e0 + i) * BNn);
      float a = 0.f;
#pragma unroll
      for (int q = 0; q < 8; ++q) {
        f4 u = ur[q];
        a = fmaf(hh[q * 4 + 0], u.x, a);
        a = fmaf(hh[q * 4 + 1], u.y, a);
        a = fmaf(hh[q * 4 + 2], u.z, a);
        a = fmaf(hh[q * 4 + 3], u.w, a);
      }
      x[i] = a + fl[s][e0 + i] + up_b[lang * En + e0 + i];
      s1 += x[i];
      s2 = fmaf(x[i], x[i], s2);
    }
#pragma unroll
    for (int off = 32; off >= 1; off >>= 1) {
      s1 += __shfl_xor(s1, off);
      s2 += __shfl_xor(s2, off);
    }
    const float mu = s1 * (1.0f / En);
    const float var = s2 * (1.0f / En) - mu * mu;
    const float rs = rsqrtf(var + 1e-5f);
#pragma unroll
    for (int i = 0; i < 4; ++i) {
      const float yv = (x[i] - mu) * rs * ln_g[lang * En + e0 + i] + ln_b[lang * En + e0 + i];
      yA[s][e0 + i] = (f16)yv;
    }
  }
  __syncthreads();

  // proj: wave wv covers o in [wv*64, wv*64+64)
  const int lr = ln & 15, lg = ln >> 4;
  f4 acc[4];
#pragma unroll
  for (int tt = 0; tt < 4; ++tt) {
    const float pb = proj_b[wv * 64 + tt * 16 + lr];
    acc[tt] = (f4){pb, pb, pb, pb};
  }
#pragma unroll
  for (int kk = 0; kk < 8; ++kk) {
    h8 aF = *(const h8*)(&yA[lr][kk * 32 + lg * 8]);
#pragma unroll
    for (int tt = 0; tt < 4; ++tt) {
      const int o0 = wv * 64 + tt * 16;
      const float* pw = proj_w + (o0 + lr) * En + kk * 32 + lg * 8;
      h8 bF;
#pragma unroll
      for (int i = 0; i < 8; ++i) bF[i] = (f16)pw[i];
      acc[tt] = __builtin_amdgcn_mfma_f32_16x16x32_f16(aF, bF, acc[tt], 0, 0, 0);
    }
  }
  if (lg < 2) {
#pragma unroll
    for (int tt = 0; tt < 4; ++tt) {
      const int o0 = wv * 64 + tt * 16;
#pragma unroll
      for (int r = 0; r < 4; ++r)
        out[(b0 + lg * 4 + r) * On + o0 + lr] = acc[tt][r];
    }
  }
}

extern "C" void kernel_launch(void* const* d_in, const int* in_sizes, int n_in,
                              void* d_out, int out_size, void* d_ws, size_t ws_size,
                              hipStream_t stream) {
  const int* tokens = (const int*)d_in[0];
  const int* lang_ids = (const int*)d_in[1];
  const float* emb = (const float*)d_in[2];
  const float* w_ih_f = (const float*)d_in[3];
  const float* w_hh_f = (const float*)d_in[4];
  const float* b_ih_f = (const float*)d_in[5];
  const float* b_hh_f = (const float*)d_in[6];
  const float* w_ih_b = (const float*)d_in[7];
  const float* w_hh_b = (const float*)d_in[8];
  const float* b_ih_b = (const float*)d_in[9];
  const float* b_hh_b = (const float*)d_in[10];
  const float* down_w = (const float*)d_in[11];
  const float* down_b = (const float*)d_in[12];
  const float* up_w = (const float*)d_in[13];
  const float* up_b = (const float*)d_in[14];
  const float* ln_g = (const float*)d_in[15];
  const float* ln_b = (const float*)d_in[16];
  const float* proj_w = (const float*)d_in[17];
  const float* proj_b = (const float*)d_in[18];

  f16* xt = (f16*)d_ws;                                       // [2][256][128][4] f16 = 512KB
  float* feat = (float*)((char*)d_ws + 2 * Vn * Hn * 4 * 2);  // [2048][256] f32

  build_table_k<<<dim3(512), dim3(128), 0, stream>>>(emb, w_ih_f, b_ih_f, w_ih_b, b_ih_b, xt);
  gru_k<<<dim3(256), dim3(512), 0, stream>>>(tokens, w_hh_f, b_hh_f, w_hh_b, b_hh_b, xt, feat);
  epi_k<<<dim3(256), dim3(256), 0, stream>>>(feat, lang_ids, down_w, down_b, up_w, up_b,
                                             ln_g, ln_b, proj_w, proj_b, (float*)d_out);
}